// Round 3
// 1546.496 us; speedup vs baseline: 1.3565x; 1.3565x over previous
//
#include <hip/hip_runtime.h>
#include <hip/hip_bf16.h>
#include <stdint.h>

#define DECAY 0.951229424500714f

// problem sizes (fixed by setup_inputs)
#define BATCH 16
#define TSTEPS 16

// ---------------- ws layout (byte offsets) ----------------
// conv-phase state (dead after conv loop; overlaid by split-K partials):
#define OFF_VM0B 0u            // fp32 [16][4096][32] NHWC          8,388,608 B
#define OFF_VM1B 8388608u      // fp32 [16][64][64][64] NCHW       16,777,216 B
#define OFF_S0PB 25165824u     // bf16 [16][32][66][66] padded NCHW 4,460,544 B
#define OFF_W0TB 29626368u     // fp32 [18 (ic*9+tap)][32 oc]           2,304 B
#define ZERO_BYTES 29626368u   // vm0+vm1+s0p (guard ring must be 0)
// persistent across dense phase:
#define KSPLIT 64
#define KCHUNK (65536 / KSPLIT)        // 1024
#define OFF_PART_BYTES 0u              // fp32 [64][256][512] = 33,554,432 B (overlays dead conv state)
#define OFF_I_BYTES 33554432u          // fp32 [256][512] (m = t*16+b)
#define OFF_FLAT_BYTES 34078720u       // bf16 [256][65536]  (ends at 67,633,152 B)

typedef __attribute__((ext_vector_type(8))) short short8;
typedef __attribute__((ext_vector_type(4))) float floatx4;

__device__ inline unsigned short f2bf_rne(float f) {
    unsigned u = __float_as_uint(f);
    unsigned r = (u + 0x7FFFu + ((u >> 16) & 1u)) >> 16;
    return (unsigned short)r;
}
__device__ inline float bf2f(unsigned short h) {
    return __uint_as_float(((unsigned)h) << 16);
}

// ---------------- weight prep (once per call): W0 transpose only ----------------
// W0t[(ic*9+tap)][oc] fp32 — exact copy, just rearranged for coalesced conv0 reads
__global__ __launch_bounds__(256) void prep_weights(const float* __restrict__ W0,
                                                    float* __restrict__ ws) {
    int id = blockIdx.x * 256 + threadIdx.x;
    if (id < 576) {
        int ict = id >> 5, oc = id & 31;      // ict = ic*9 + tap
        int ic = ict / 9, tap = ict % 9;
        float* w0t = (float*)((char*)ws + OFF_W0TB);
        w0t[ict * 32 + oc] = W0[(oc * 2 + ic) * 9 + tap];
    }
}

// ---------------- conv0 (2->32, 3x3, pad 1) + LIF0 -> s0 bf16 padded-NCHW ----------------
// Arithmetic bit-identical to the verified round-0 kernel (same fma order, same LIF algebra;
// s_prev recomputed from vm0 since s0_prev == (vm0_prev > 0.5)).
__global__ __launch_bounds__(256) void conv0_lif(const float* __restrict__ in,
                                                 float* __restrict__ ws, int t) {
    int y = blockIdx.x, b = blockIdx.y;
    int tid = threadIdx.x;
    int x = tid & 63;
    int g = __builtin_amdgcn_readfirstlane(tid >> 6);   // oc group (8 oc)
    const float* xin = in + (size_t)((b * TSTEPS + t) * 2) * 4096;
    const float* w0t = (const float*)((const char*)ws + OFF_W0TB);
    float acc[8];
#pragma unroll
    for (int u = 0; u < 8; ++u) acc[u] = 0.f;
#pragma unroll
    for (int ic = 0; ic < 2; ++ic) {
#pragma unroll
        for (int dy = 0; dy < 3; ++dy) {
            int sy = y + dy - 1;
            bool vy = (unsigned)sy < 64u;
            const float* rp = xin + ic * 4096 + sy * 64;
#pragma unroll
            for (int dx = 0; dx < 3; ++dx) {
                int sx = x + dx - 1;
                float v = (vy && (unsigned)sx < 64u) ? rp[sx] : 0.f;
                v = fminf(fmaxf(v, 0.f), 1.f);          // clip(x,0,1)
                const float* wp = w0t + ((ic * 9 + dy * 3 + dx) * 32 + g * 8);
#pragma unroll
                for (int u = 0; u < 8; ++u) acc[u] = fmaf(v, wp[u], acc[u]);
            }
        }
    }
    // LIF0 on vm0 (NHWC fp32); spikes out to padded NCHW bf16 s0 (exact 0.0 / 1.0)
    float* vm0 = (float*)((char*)ws + OFF_VM0B);
    size_t pidx = ((size_t)(b * 4096 + y * 64 + x)) * 32 + g * 8;
    floatx4 v0 = *(floatx4*)(vm0 + pidx);
    floatx4 v1 = *(floatx4*)(vm0 + pidx + 4);
    unsigned short sp[8];
#pragma unroll
    for (int u = 0; u < 4; ++u) {
        float vm = ((v0[u] > 0.5f) ? 0.f : v0[u] * DECAY) + acc[u];
        v0[u] = vm;
        sp[u] = (vm > 0.5f) ? (unsigned short)0x3F80 : (unsigned short)0;
    }
#pragma unroll
    for (int u = 0; u < 4; ++u) {
        float vm = ((v1[u] > 0.5f) ? 0.f : v1[u] * DECAY) + acc[4 + u];
        v1[u] = vm;
        sp[4 + u] = (vm > 0.5f) ? (unsigned short)0x3F80 : (unsigned short)0;
    }
    *(floatx4*)(vm0 + pidx) = v0;
    *(floatx4*)(vm0 + pidx + 4) = v1;
    unsigned short* s0p = (unsigned short*)((char*)ws + OFF_S0PB);
    // padded NCHW: [(b*32+c)][y+1][x+1], row pitch 66, plane 4356; guard ring stays 0
#pragma unroll
    for (int u = 0; u < 8; ++u) {
        int c = g * 8 + u;
        s0p[((size_t)(b * 32 + c) * 66 + (y + 1)) * 66 + (x + 1)] = sp[u];
    }
}

// ---------------- conv1 (32->64, 3x3, pad 1) + LIF1 + fused 2x2 maxpool ----------------
// BIT-EXACT round-0 arithmetic: per output, acc = sequential fp32 fma over
// (ic=0..31 outer, tap=0..8 inner) with v in {0.0,1.0} (bf16 storage is exact) and
// W1 fp32 read directly (wave-uniform -> s_loads). LIF algebra identical (s_prev from vm).
// Thread = (x lane, 16 oc); computes BOTH rows of a pooled pair, sharing the 12 s0 loads/ic.
// Pool: spike max over 2x2 == bitwise OR of {0,0x3F80} patterns (decision-identical).
__global__ __launch_bounds__(256) void conv1_lif(const float* __restrict__ W1,
                                                 float* __restrict__ ws, int t) {
    __shared__ unsigned short s1_s[2][64][68];   // [row-in-pair][x][oc] (pitch 68)
    int tid = threadIdx.x;
    int x = tid & 63;
    int ocg = __builtin_amdgcn_readfirstlane(tid >> 6);  // 16 oc per thread
    int y2 = blockIdx.x, b = blockIdx.y;                 // y2 = pooled row
    int y0 = y2 * 2;
    const unsigned short* s0 = (const unsigned short*)((const char*)ws + OFF_S0PB);

    float acc0[16], acc1[16];
#pragma unroll
    for (int u = 0; u < 16; ++u) { acc0[u] = 0.f; acc1[u] = 0.f; }

    for (int ic = 0; ic < 32; ++ic) {
        // padded rows y0..y0+3, cols x..x+2 (output row y reads padded rows y..y+2)
        const unsigned short* sc = s0 + ((size_t)(b * 32 + ic) * 66 + y0) * 66 + x;
        float v[12];
#pragma unroll
        for (int rr = 0; rr < 4; ++rr)
#pragma unroll
            for (int dx = 0; dx < 3; ++dx)
                v[rr * 3 + dx] = bf2f(sc[rr * 66 + dx]);
#pragma unroll
        for (int u = 0; u < 16; ++u) {
            const float* wp = W1 + ((size_t)(ocg * 16 + u) * 32 + ic) * 9;  // uniform -> s_load
#pragma unroll
            for (int k = 0; k < 9; ++k) {
                acc0[u] = fmaf(v[k],     wp[k], acc0[u]);   // row y0:   v rows 0..2
                acc1[u] = fmaf(v[3 + k], wp[k], acc1[u]);   // row y0+1: v rows 1..3
            }
        }
    }

    // LIF1 on vm1 (NCHW fp32; s_prev = vm_prev > 0.5); spikes to LDS for pooling
    float* vm1 = (float*)((char*)ws + OFF_VM1B);
#pragma unroll
    for (int u = 0; u < 16; ++u) {
        int oc = ocg * 16 + u;
        size_t base = (size_t)(b * 64 + oc) * 4096 + y0 * 64 + x;
        float vma = vm1[base];
        vma = ((vma > 0.5f) ? 0.f : vma * DECAY) + acc0[u];
        vm1[base] = vma;
        s1_s[0][x][oc] = (vma > 0.5f) ? (unsigned short)0x3F80 : (unsigned short)0;
        float vmb = vm1[base + 64];
        vmb = ((vmb > 0.5f) ? 0.f : vmb * DECAY) + acc1[u];
        vm1[base + 64] = vmb;
        s1_s[1][x][oc] = (vmb > 0.5f) ? (unsigned short)0x3F80 : (unsigned short)0;
    }
    __syncthreads();

    // fused 2x2 maxpool -> flat[t*16+b] (spikes in {0,0x3F80} => max == bitwise OR)
    unsigned short* flat = (unsigned short*)((char*)ws + OFF_FLAT_BYTES)
                           + (size_t)(t * 16 + b) * 65536;
#pragma unroll
    for (int it = 0; it < 8; ++it) {
        int c = (tid >> 5) + it * 8;
        int x2 = tid & 31;
        unsigned short v = (unsigned short)(s1_s[0][2 * x2][c] | s1_s[0][2 * x2 + 1][c]
                                          | s1_s[1][2 * x2][c] | s1_s[1][2 * x2 + 1][c]);
        flat[c * 1024 + y2 * 32 + x2] = v;
    }
}

// ---------------- dense0 via bf16 MFMA, hi/lo weight split (verified round-0 code) ----------------
__global__ __launch_bounds__(256) void dense0_mfma(const float* __restrict__ D0,
                                                   float* __restrict__ ws) {
    __shared__ unsigned short A_s[256 * 72];   // [m][k] bf16
    __shared__ unsigned short Bh_s[64 * 72];   // [n][k] bf16 hi
    __shared__ unsigned short Bl_s[64 * 72];   // [n][k] bf16 lo
    int tid = threadIdx.x;
    int nb = blockIdx.x, kc = blockIdx.y;
    int lane = tid & 63, w = tid >> 6, q = lane >> 4, r = lane & 15;
    const unsigned short* flat = (const unsigned short*)((const char*)ws + OFF_FLAT_BYTES);
    const size_t kbase = (size_t)kc * KCHUNK;

    floatx4 acc[4][4];
#pragma unroll
    for (int i = 0; i < 4; ++i)
#pragma unroll
        for (int j = 0; j < 4; ++j) acc[i][j] = (floatx4){0.f, 0.f, 0.f, 0.f};

    const unsigned short* aG = flat + (size_t)tid * 65536 + kbase;
    int bn = tid & 63, bks = (tid >> 6) * 16;
    const float* bG = D0 + (size_t)(nb * 64 + bn) * 65536 + kbase + bks;

    for (int k0 = 0; k0 < KCHUNK; k0 += 64) {
        uint4 av[8];
#pragma unroll
        for (int i = 0; i < 8; ++i) av[i] = *(const uint4*)(aG + k0 + i * 8);
        float4 bv[4];
#pragma unroll
        for (int j = 0; j < 4; ++j) bv[j] = *(const float4*)(bG + k0 + j * 4);

        __syncthreads();
#pragma unroll
        for (int i = 0; i < 8; ++i) *(uint4*)&A_s[tid * 72 + i * 8] = av[i];

        float f[16];
#pragma unroll
        for (int j = 0; j < 4; ++j) { f[j*4+0]=bv[j].x; f[j*4+1]=bv[j].y; f[j*4+2]=bv[j].z; f[j*4+3]=bv[j].w; }
        unsigned hw[8], lw[8];
#pragma unroll
        for (int j = 0; j < 8; ++j) {
            unsigned short h0 = f2bf_rne(f[2*j]),   h1 = f2bf_rne(f[2*j+1]);
            unsigned short l0 = f2bf_rne(f[2*j]   - bf2f(h0));
            unsigned short l1 = f2bf_rne(f[2*j+1] - bf2f(h1));
            hw[j] = (unsigned)h0 | ((unsigned)h1 << 16);
            lw[j] = (unsigned)l0 | ((unsigned)l1 << 16);
        }
        *(uint4*)&Bh_s[bn * 72 + bks]     = make_uint4(hw[0], hw[1], hw[2], hw[3]);
        *(uint4*)&Bh_s[bn * 72 + bks + 8] = make_uint4(hw[4], hw[5], hw[6], hw[7]);
        *(uint4*)&Bl_s[bn * 72 + bks]     = make_uint4(lw[0], lw[1], lw[2], lw[3]);
        *(uint4*)&Bl_s[bn * 72 + bks + 8] = make_uint4(lw[4], lw[5], lw[6], lw[7]);
        __syncthreads();

#pragma unroll
        for (int ks = 0; ks < 64; ks += 32) {
            short8 af[4];
#pragma unroll
            for (int mi = 0; mi < 4; ++mi)
                af[mi] = *(const short8*)&A_s[(w * 64 + mi * 16 + r) * 72 + ks + q * 8];
#pragma unroll
            for (int ni = 0; ni < 4; ++ni) {
                short8 bh = *(const short8*)&Bh_s[(ni * 16 + r) * 72 + ks + q * 8];
                short8 bl = *(const short8*)&Bl_s[(ni * 16 + r) * 72 + ks + q * 8];
#pragma unroll
                for (int mi = 0; mi < 4; ++mi) {
                    acc[mi][ni] = __builtin_amdgcn_mfma_f32_16x16x32_bf16(af[mi], bh, acc[mi][ni], 0, 0, 0);
                    acc[mi][ni] = __builtin_amdgcn_mfma_f32_16x16x32_bf16(af[mi], bl, acc[mi][ni], 0, 0, 0);
                }
            }
        }
    }

    float* part = (float*)((char*)ws + OFF_PART_BYTES);
#pragma unroll
    for (int mi = 0; mi < 4; ++mi)
#pragma unroll
        for (int ni = 0; ni < 4; ++ni) {
            int m0 = w * 64 + mi * 16 + q * 4;
            int n  = nb * 64 + ni * 16 + r;
#pragma unroll
            for (int rg = 0; rg < 4; ++rg)
                part[((size_t)kc * 256 + m0 + rg) * 512 + n] = acc[mi][ni][rg];
        }
}

// ---------------- reduce split-K partials (verified round-0 code) ----------------
__global__ __launch_bounds__(256) void reduce_part(float* __restrict__ ws) {
    int e = blockIdx.x * 256 + threadIdx.x;    // 0..131071
    const float* part = (const float*)((const char*)ws + OFF_PART_BYTES);
    float s = 0.f;
#pragma unroll 8
    for (int c = 0; c < KSPLIT; ++c) s += part[(size_t)c * 131072 + e];
    ((float*)((char*)ws + OFF_I_BYTES))[e] = s;
}

// ---------------- tail: LIF2 + dense1 + LIF3 + acc over all t (verified round-0 code) ----------------
__global__ __launch_bounds__(512) void tail_kernel(const float* __restrict__ D1,
                                                   float* __restrict__ out,
                                                   const float* __restrict__ ws_ro) {
    __shared__ float s2l[16][512];
    __shared__ float d1l[11 * 512];
    __shared__ float pb[2][176];
    int tid = threadIdx.x;
    for (int i = tid; i < 11 * 512; i += 512) d1l[i] = D1[i];
    const float* Ibuf = (const float*)((const char*)ws_ro + OFF_I_BYTES);

    float vm2[16];
#pragma unroll
    for (int i = 0; i < 16; ++i) vm2[i] = 0.f;
    unsigned s2mask = 0;
    float vm3 = 0.f, s3 = 0.f, accv = 0.f;
    int rb = tid / 11, ro = tid % 11;
    __syncthreads();

    for (int t = 0; t < TSTEPS; ++t) {
        {
            int j = tid;
#pragma unroll
            for (int b = 0; b < 16; ++b) {
                float I = Ibuf[(size_t)(t * 16 + b) * 512 + j];
                float sp = ((s2mask >> b) & 1u) ? 1.f : 0.f;
                float vm = vm2[b] * DECAY * (1.f - sp) + I;
                vm2[b] = vm;
                unsigned sb = (vm > 0.5f) ? 1u : 0u;
                s2mask = (s2mask & ~(1u << b)) | (sb << b);
                s2l[b][j] = (float)sb;
            }
        }
        __syncthreads();
        if (tid < 352) {
            int g = tid / 176, rr = tid % 176;
            int b = rr / 11, o = rr % 11;
            float p = 0.f;
            int kbase = g * 256;
            for (int k = 0; k < 256; ++k)
                p = fmaf(s2l[b][kbase + k], d1l[o * 512 + kbase + k], p);
            pb[g][rr] = p;
        }
        __syncthreads();
        if (tid < 176) {
            float I3 = pb[0][tid] + pb[1][tid];
            float vm = vm3 * DECAY * (1.f - s3) + I3;
            vm3 = vm;
            s3 = (vm > 0.5f) ? 1.f : 0.f;
            accv += s3;
        }
        __syncthreads();
    }
    if (tid < 176) out[rb * 11 + ro] = accv * (1.f / 16.f);
}

extern "C" void kernel_launch(void* const* d_in, const int* in_sizes, int n_in,
                              void* d_out, int out_size, void* d_ws, size_t ws_size,
                              hipStream_t stream) {
    (void)in_sizes; (void)n_in; (void)out_size; (void)ws_size;
    const float* in = (const float*)d_in[0];
    const float* W0 = (const float*)d_in[1];
    const float* W1 = (const float*)d_in[2];
    const float* D0 = (const float*)d_in[3];
    const float* D1 = (const float*)d_in[4];
    float* ws = (float*)d_ws;
    float* out = (float*)d_out;

    // zero persistent LIF state (vm0, vm1) + padded s0 (guard ring) — ws is poisoned each call
    hipMemsetAsync(d_ws, 0, ZERO_BYTES, stream);
    prep_weights<<<3, 256, 0, stream>>>(W0, ws);

    for (int t = 0; t < TSTEPS; ++t) {
        conv0_lif<<<dim3(64, 16), 256, 0, stream>>>(in, ws, t);
        conv1_lif<<<dim3(32, 16), 256, 0, stream>>>(W1, ws, t);
    }
    dense0_mfma<<<dim3(8, KSPLIT), 256, 0, stream>>>(D0, ws);
    reduce_part<<<512, 256, 0, stream>>>(ws);
    tail_kernel<<<1, 512, 0, stream>>>(D1, out, ws);
}

// Round 4
// 1532.301 us; speedup vs baseline: 1.3690x; 1.0093x over previous
//
#include <hip/hip_runtime.h>
#include <hip/hip_bf16.h>
#include <stdint.h>

#define DECAY 0.951229424500714f

// problem sizes (fixed by setup_inputs)
#define BATCH 16
#define TSTEPS 16

// ---------------- ws layout (byte offsets) ----------------
// conv-phase state (dead after conv loop; overlaid by split-K partials):
#define OFF_VM0B 0u            // fp32 [16][4096][32] NHWC          8,388,608 B
#define OFF_VM1B 8388608u      // fp32 [16][64][64][64] NCHW       16,777,216 B
#define OFF_S0PB 25165824u     // bf16 [16][32][66][66] padded NCHW 4,460,544 B
#define OFF_W0TB 29626368u     // fp32 [18 (ic*9+tap)][32 oc]           2,304 B
#define OFF_W1TB 29628672u     // fp32 [4 ocg][32 ic][16 u][9 k]       73,728 B
#define ZERO_BYTES 29626368u   // vm0+vm1+s0p (guard ring must be 0)
// persistent across dense phase:
#define KSPLIT 64
#define KCHUNK (65536 / KSPLIT)        // 1024
#define OFF_PART_BYTES 0u              // fp32 [64][256][512] = 33,554,432 B (overlays dead conv state + W0t/W1t)
#define OFF_I_BYTES 33554432u          // fp32 [256][512] (m = t*16+b)
#define OFF_FLAT_BYTES 34078720u       // bf16 [256][65536]  (ends at 67,633,152 B)

typedef __attribute__((ext_vector_type(8))) short short8;
typedef __attribute__((ext_vector_type(4))) float floatx4;

__device__ inline unsigned short f2bf_rne(float f) {
    unsigned u = __float_as_uint(f);
    unsigned r = (u + 0x7FFFu + ((u >> 16) & 1u)) >> 16;
    return (unsigned short)r;
}
__device__ inline float bf2f(unsigned short h) {
    return __uint_as_float(((unsigned)h) << 16);
}

// ---------------- weight prep (once per call): exact fp32 transposes ----------------
// W1t[ocg][ic][u][k]  (contiguous 144 floats per (ocg,ic) -> few s_load_dwordx16)
// W0t[(ic*9+tap)][oc]
__global__ __launch_bounds__(256) void prep_weights(const float* __restrict__ W0,
                                                    const float* __restrict__ W1,
                                                    float* __restrict__ ws) {
    int id = blockIdx.x * 256 + threadIdx.x;
    if (id < 18432) {
        int oc = id / 288, rem = id % 288, ic = rem / 9, k = rem % 9;
        int ocg = oc >> 4, u = oc & 15;
        float* w1t = (float*)((char*)ws + OFF_W1TB);
        w1t[((ocg * 32 + ic) * 16 + u) * 9 + k] = W1[((size_t)oc * 32 + ic) * 9 + k];
    } else if (id < 19008) {
        int e = id - 18432;
        int ict = e >> 5, oc = e & 31;      // ict = ic*9 + tap
        int ic = ict / 9, tap = ict % 9;
        float* w0t = (float*)((char*)ws + OFF_W0TB);
        w0t[ict * 32 + oc] = W0[(oc * 2 + ic) * 9 + tap];
    }
}

// ---------------- conv0 (2->32, 3x3, pad 1) + LIF0 -> s0 bf16 padded-NCHW ----------------
// Arithmetic bit-identical to the verified round-0 kernel.
__global__ __launch_bounds__(256) void conv0_lif(const float* __restrict__ in,
                                                 float* __restrict__ ws, int t) {
    int y = blockIdx.x, b = blockIdx.y;
    int tid = threadIdx.x;
    int x = tid & 63;
    int g = __builtin_amdgcn_readfirstlane(tid >> 6);   // oc group (8 oc)
    const float* xin = in + (size_t)((b * TSTEPS + t) * 2) * 4096;
    const float* w0t = (const float*)((const char*)ws + OFF_W0TB);
    float acc[8];
#pragma unroll
    for (int u = 0; u < 8; ++u) acc[u] = 0.f;
#pragma unroll
    for (int ic = 0; ic < 2; ++ic) {
#pragma unroll
        for (int dy = 0; dy < 3; ++dy) {
            int sy = y + dy - 1;
            bool vy = (unsigned)sy < 64u;
            const float* rp = xin + ic * 4096 + sy * 64;
#pragma unroll
            for (int dx = 0; dx < 3; ++dx) {
                int sx = x + dx - 1;
                float v = (vy && (unsigned)sx < 64u) ? rp[sx] : 0.f;
                v = fminf(fmaxf(v, 0.f), 1.f);          // clip(x,0,1)
                const float* wp = w0t + ((ic * 9 + dy * 3 + dx) * 32 + g * 8);
#pragma unroll
                for (int u = 0; u < 8; ++u) acc[u] = fmaf(v, wp[u], acc[u]);
            }
        }
    }
    // LIF0 on vm0 (NHWC fp32); spikes out to padded NCHW bf16 s0 (exact 0.0 / 1.0)
    float* vm0 = (float*)((char*)ws + OFF_VM0B);
    size_t pidx = ((size_t)(b * 4096 + y * 64 + x)) * 32 + g * 8;
    floatx4 v0 = *(floatx4*)(vm0 + pidx);
    floatx4 v1 = *(floatx4*)(vm0 + pidx + 4);
    unsigned short sp[8];
#pragma unroll
    for (int u = 0; u < 4; ++u) {
        float vm = ((v0[u] > 0.5f) ? 0.f : v0[u] * DECAY) + acc[u];
        v0[u] = vm;
        sp[u] = (vm > 0.5f) ? (unsigned short)0x3F80 : (unsigned short)0;
    }
#pragma unroll
    for (int u = 0; u < 4; ++u) {
        float vm = ((v1[u] > 0.5f) ? 0.f : v1[u] * DECAY) + acc[4 + u];
        v1[u] = vm;
        sp[4 + u] = (vm > 0.5f) ? (unsigned short)0x3F80 : (unsigned short)0;
    }
    *(floatx4*)(vm0 + pidx) = v0;
    *(floatx4*)(vm0 + pidx + 4) = v1;
    unsigned short* s0p = (unsigned short*)((char*)ws + OFF_S0PB);
#pragma unroll
    for (int u = 0; u < 8; ++u) {
        int c = g * 8 + u;
        s0p[((size_t)(b * 32 + c) * 66 + (y + 1)) * 66 + (x + 1)] = sp[u];
    }
}

// ---------------- conv1 (32->64, 3x3, pad 1) + LIF1 + fused 2x2 maxpool ----------------
// BIT-EXACT round-3 arithmetic (sequential fp32 fma, ic outer / u / k inner; two
// independent chains acc0/acc1). v2: s0 tile staged to LDS as fp32 (identical values),
// weights from contiguous W1t (exact copy) -> latency off the critical path.
__global__ __launch_bounds__(256) void conv1_lif(float* __restrict__ ws, int t) {
    __shared__ float s0t[32][4][68];             // [ic][padded row rr][col] (pitch 68)
    __shared__ unsigned short s1_s[2][64][68];   // [row-in-pair][x][oc]
    int tid = threadIdx.x;
    int x = tid & 63;
    int ocg = __builtin_amdgcn_readfirstlane(tid >> 6);  // 16 oc per thread
    int y2 = blockIdx.x, b = blockIdx.y;                 // y2 = pooled row
    int y0 = y2 * 2;

    // ---- stage s0 (bf16 -> fp32), rows y0..y0+3 of all 32 ic, coalesced ----
    {
        const unsigned short* base = (const unsigned short*)((const char*)ws + OFF_S0PB)
                                     + (size_t)b * 32 * 4356 + (size_t)y0 * 66;
#pragma unroll
        for (int it = 0; it < 33; ++it) {
            int e = tid + it * 256;             // 0..8447 = ic*264 + rr*66 + col
            int ic = e / 264;
            int rem = e - ic * 264;
            int rr = rem / 66;
            int col = rem - rr * 66;
            s0t[ic][rr][col] = bf2f(base[(size_t)ic * 4356 + rr * 66 + col]);
        }
    }
    __syncthreads();

    float acc0[16], acc1[16];
#pragma unroll
    for (int u = 0; u < 16; ++u) { acc0[u] = 0.f; acc1[u] = 0.f; }

    const float* w1t = (const float*)((const char*)ws + OFF_W1TB) + (size_t)ocg * 32 * 144;

    for (int ic = 0; ic < 32; ++ic) {
        float va[4][3];
#pragma unroll
        for (int rr = 0; rr < 4; ++rr)
#pragma unroll
            for (int dx = 0; dx < 3; ++dx)
                va[rr][dx] = s0t[ic][rr][x + dx];
        const float* wp = w1t + ic * 144;       // 144 contiguous floats (uniform -> s_load)
#pragma unroll
        for (int u = 0; u < 16; ++u) {
#pragma unroll
            for (int k = 0; k < 9; ++k) {
                int rr = k / 3, dx = k - rr * 3;
                float w = wp[u * 9 + k];
                acc0[u] = fmaf(va[rr][dx],     w, acc0[u]);   // output row y0
                acc1[u] = fmaf(va[rr + 1][dx], w, acc1[u]);   // output row y0+1
            }
        }
    }

    // LIF1 on vm1 (NCHW fp32; s_prev = vm_prev > 0.5); spikes to LDS for pooling
    float* vm1 = (float*)((char*)ws + OFF_VM1B);
#pragma unroll
    for (int u = 0; u < 16; ++u) {
        int oc = ocg * 16 + u;
        size_t base = (size_t)(b * 64 + oc) * 4096 + y0 * 64 + x;
        float vma = vm1[base];
        vma = ((vma > 0.5f) ? 0.f : vma * DECAY) + acc0[u];
        vm1[base] = vma;
        s1_s[0][x][oc] = (vma > 0.5f) ? (unsigned short)0x3F80 : (unsigned short)0;
        float vmb = vm1[base + 64];
        vmb = ((vmb > 0.5f) ? 0.f : vmb * DECAY) + acc1[u];
        vm1[base + 64] = vmb;
        s1_s[1][x][oc] = (vmb > 0.5f) ? (unsigned short)0x3F80 : (unsigned short)0;
    }
    __syncthreads();

    // fused 2x2 maxpool -> flat[t*16+b] (spikes in {0,0x3F80} => max == bitwise OR)
    unsigned short* flat = (unsigned short*)((char*)ws + OFF_FLAT_BYTES)
                           + (size_t)(t * 16 + b) * 65536;
#pragma unroll
    for (int it = 0; it < 8; ++it) {
        int c = (tid >> 5) + it * 8;
        int x2 = tid & 31;
        unsigned short v = (unsigned short)(s1_s[0][2 * x2][c] | s1_s[0][2 * x2 + 1][c]
                                          | s1_s[1][2 * x2][c] | s1_s[1][2 * x2 + 1][c]);
        flat[c * 1024 + y2 * 32 + x2] = v;
    }
}

// ---------------- dense0 via bf16 MFMA, hi/lo weight split (verified) ----------------
// Grid swapped to (kc, nb): linear block id = nb*64 + kc -> XCD = kc % 8, so all 8
// nb-blocks of one kc share an XCD L2 and the flat chunk is HBM-fetched ~once.
__global__ __launch_bounds__(256) void dense0_mfma(const float* __restrict__ D0,
                                                   float* __restrict__ ws) {
    __shared__ unsigned short A_s[256 * 72];   // [m][k] bf16
    __shared__ unsigned short Bh_s[64 * 72];   // [n][k] bf16 hi
    __shared__ unsigned short Bl_s[64 * 72];   // [n][k] bf16 lo
    int tid = threadIdx.x;
    int kc = blockIdx.x, nb = blockIdx.y;
    int lane = tid & 63, w = tid >> 6, q = lane >> 4, r = lane & 15;
    const unsigned short* flat = (const unsigned short*)((const char*)ws + OFF_FLAT_BYTES);
    const size_t kbase = (size_t)kc * KCHUNK;

    floatx4 acc[4][4];
#pragma unroll
    for (int i = 0; i < 4; ++i)
#pragma unroll
        for (int j = 0; j < 4; ++j) acc[i][j] = (floatx4){0.f, 0.f, 0.f, 0.f};

    const unsigned short* aG = flat + (size_t)tid * 65536 + kbase;
    int bn = tid & 63, bks = (tid >> 6) * 16;
    const float* bG = D0 + (size_t)(nb * 64 + bn) * 65536 + kbase + bks;

    for (int k0 = 0; k0 < KCHUNK; k0 += 64) {
        uint4 av[8];
#pragma unroll
        for (int i = 0; i < 8; ++i) av[i] = *(const uint4*)(aG + k0 + i * 8);
        float4 bv[4];
#pragma unroll
        for (int j = 0; j < 4; ++j) bv[j] = *(const float4*)(bG + k0 + j * 4);

        __syncthreads();
#pragma unroll
        for (int i = 0; i < 8; ++i) *(uint4*)&A_s[tid * 72 + i * 8] = av[i];

        float f[16];
#pragma unroll
        for (int j = 0; j < 4; ++j) { f[j*4+0]=bv[j].x; f[j*4+1]=bv[j].y; f[j*4+2]=bv[j].z; f[j*4+3]=bv[j].w; }
        unsigned hw[8], lw[8];
#pragma unroll
        for (int j = 0; j < 8; ++j) {
            unsigned short h0 = f2bf_rne(f[2*j]),   h1 = f2bf_rne(f[2*j+1]);
            unsigned short l0 = f2bf_rne(f[2*j]   - bf2f(h0));
            unsigned short l1 = f2bf_rne(f[2*j+1] - bf2f(h1));
            hw[j] = (unsigned)h0 | ((unsigned)h1 << 16);
            lw[j] = (unsigned)l0 | ((unsigned)l1 << 16);
        }
        *(uint4*)&Bh_s[bn * 72 + bks]     = make_uint4(hw[0], hw[1], hw[2], hw[3]);
        *(uint4*)&Bh_s[bn * 72 + bks + 8] = make_uint4(hw[4], hw[5], hw[6], hw[7]);
        *(uint4*)&Bl_s[bn * 72 + bks]     = make_uint4(lw[0], lw[1], lw[2], lw[3]);
        *(uint4*)&Bl_s[bn * 72 + bks + 8] = make_uint4(lw[4], lw[5], lw[6], lw[7]);
        __syncthreads();

#pragma unroll
        for (int ks = 0; ks < 64; ks += 32) {
            short8 af[4];
#pragma unroll
            for (int mi = 0; mi < 4; ++mi)
                af[mi] = *(const short8*)&A_s[(w * 64 + mi * 16 + r) * 72 + ks + q * 8];
#pragma unroll
            for (int ni = 0; ni < 4; ++ni) {
                short8 bh = *(const short8*)&Bh_s[(ni * 16 + r) * 72 + ks + q * 8];
                short8 bl = *(const short8*)&Bl_s[(ni * 16 + r) * 72 + ks + q * 8];
#pragma unroll
                for (int mi = 0; mi < 4; ++mi) {
                    acc[mi][ni] = __builtin_amdgcn_mfma_f32_16x16x32_bf16(af[mi], bh, acc[mi][ni], 0, 0, 0);
                    acc[mi][ni] = __builtin_amdgcn_mfma_f32_16x16x32_bf16(af[mi], bl, acc[mi][ni], 0, 0, 0);
                }
            }
        }
    }

    float* part = (float*)((char*)ws + OFF_PART_BYTES);
#pragma unroll
    for (int mi = 0; mi < 4; ++mi)
#pragma unroll
        for (int ni = 0; ni < 4; ++ni) {
            int m0 = w * 64 + mi * 16 + q * 4;
            int n  = nb * 64 + ni * 16 + r;
#pragma unroll
            for (int rg = 0; rg < 4; ++rg)
                part[((size_t)kc * 256 + m0 + rg) * 512 + n] = acc[mi][ni][rg];
        }
}

// ---------------- reduce split-K partials (verified) ----------------
__global__ __launch_bounds__(256) void reduce_part(float* __restrict__ ws) {
    int e = blockIdx.x * 256 + threadIdx.x;    // 0..131071
    const float* part = (const float*)((const char*)ws + OFF_PART_BYTES);
    float s = 0.f;
#pragma unroll 8
    for (int c = 0; c < KSPLIT; ++c) s += part[(size_t)c * 131072 + e];
    ((float*)((char*)ws + OFF_I_BYTES))[e] = s;
}

// ---------------- tail: LIF2 + dense1 + LIF3 + acc over all t (verified) ----------------
__global__ __launch_bounds__(512) void tail_kernel(const float* __restrict__ D1,
                                                   float* __restrict__ out,
                                                   const float* __restrict__ ws_ro) {
    __shared__ float s2l[16][512];
    __shared__ float d1l[11 * 512];
    __shared__ float pb[2][176];
    int tid = threadIdx.x;
    for (int i = tid; i < 11 * 512; i += 512) d1l[i] = D1[i];
    const float* Ibuf = (const float*)((const char*)ws_ro + OFF_I_BYTES);

    float vm2[16];
#pragma unroll
    for (int i = 0; i < 16; ++i) vm2[i] = 0.f;
    unsigned s2mask = 0;
    float vm3 = 0.f, s3 = 0.f, accv = 0.f;
    int rb = tid / 11, ro = tid % 11;
    __syncthreads();

    for (int t = 0; t < TSTEPS; ++t) {
        {
            int j = tid;
#pragma unroll
            for (int b = 0; b < 16; ++b) {
                float I = Ibuf[(size_t)(t * 16 + b) * 512 + j];
                float sp = ((s2mask >> b) & 1u) ? 1.f : 0.f;
                float vm = vm2[b] * DECAY * (1.f - sp) + I;
                vm2[b] = vm;
                unsigned sb = (vm > 0.5f) ? 1u : 0u;
                s2mask = (s2mask & ~(1u << b)) | (sb << b);
                s2l[b][j] = (float)sb;
            }
        }
        __syncthreads();
        if (tid < 352) {
            int g = tid / 176, rr = tid % 176;
            int b = rr / 11, o = rr % 11;
            float p = 0.f;
            int kbase = g * 256;
            for (int k = 0; k < 256; ++k)
                p = fmaf(s2l[b][kbase + k], d1l[o * 512 + kbase + k], p);
            pb[g][rr] = p;
        }
        __syncthreads();
        if (tid < 176) {
            float I3 = pb[0][tid] + pb[1][tid];
            float vm = vm3 * DECAY * (1.f - s3) + I3;
            vm3 = vm;
            s3 = (vm > 0.5f) ? 1.f : 0.f;
            accv += s3;
        }
        __syncthreads();
    }
    if (tid < 176) out[rb * 11 + ro] = accv * (1.f / 16.f);
}

extern "C" void kernel_launch(void* const* d_in, const int* in_sizes, int n_in,
                              void* d_out, int out_size, void* d_ws, size_t ws_size,
                              hipStream_t stream) {
    (void)in_sizes; (void)n_in; (void)out_size; (void)ws_size;
    const float* in = (const float*)d_in[0];
    const float* W0 = (const float*)d_in[1];
    const float* W1 = (const float*)d_in[2];
    const float* D0 = (const float*)d_in[3];
    const float* D1 = (const float*)d_in[4];
    float* ws = (float*)d_ws;
    float* out = (float*)d_out;

    // zero persistent LIF state (vm0, vm1) + padded s0 (guard ring) — ws is poisoned each call
    hipMemsetAsync(d_ws, 0, ZERO_BYTES, stream);
    prep_weights<<<75, 256, 0, stream>>>(W0, W1, ws);

    for (int t = 0; t < TSTEPS; ++t) {
        conv0_lif<<<dim3(64, 16), 256, 0, stream>>>(in, ws, t);
        conv1_lif<<<dim3(32, 16), 256, 0, stream>>>(ws, t);
    }
    dense0_mfma<<<dim3(KSPLIT, 8), 256, 0, stream>>>(D0, ws);
    reduce_part<<<512, 256, 0, stream>>>(ws);
    tail_kernel<<<1, 512, 0, stream>>>(D1, out, ws);
}

// Round 5
// 1248.333 us; speedup vs baseline: 1.6805x; 1.2275x over previous
//
#include <hip/hip_runtime.h>
#include <hip/hip_bf16.h>
#include <stdint.h>

#define DECAY 0.951229424500714f

// problem sizes (fixed by setup_inputs)
#define BATCH 16
#define TSTEPS 16

// ---------------- ws layout (byte offsets) ----------------
// conv-phase state (dead after conv loop; overlaid by split-K partials):
#define OFF_VM0B 0u            // fp32 [16][4096][32] NHWC          8,388,608 B
#define OFF_VM1B 8388608u      // fp32 [16][64][64][64] NCHW       16,777,216 B
#define OFF_S0PB 25165824u     // bf16 [16][32][66][66] padded NCHW 4,460,544 B
#define OFF_W0TB 29626368u     // fp32 [18 (ic*9+tap)][32 oc]           2,304 B
#define OFF_W1TB 29628672u     // fp32 [4 ocg][32 ic][16 u][9 k]       73,728 B
#define ZERO_BYTES 29626368u   // vm0+vm1+s0p (guard ring must be 0)
// persistent across dense phase:
#define KSPLIT 64
#define KCHUNK (65536 / KSPLIT)        // 1024
#define OFF_PART_BYTES 0u              // fp32 [64][256][512] = 33,554,432 B (overlays dead conv state + W0t/W1t)
#define OFF_I_BYTES 33554432u          // fp32 [256][512] (m = t*16+b)
#define OFF_FLAT_BYTES 34078720u       // bf16 [256][65536]  (ends at 67,633,152 B)

typedef __attribute__((ext_vector_type(8))) short short8;
typedef __attribute__((ext_vector_type(4))) float floatx4;

__device__ inline unsigned short f2bf_rne(float f) {
    unsigned u = __float_as_uint(f);
    unsigned r = (u + 0x7FFFu + ((u >> 16) & 1u)) >> 16;
    return (unsigned short)r;
}
__device__ inline float bf2f(unsigned short h) {
    return __uint_as_float(((unsigned)h) << 16);
}

// ---------------- weight prep (once per call): exact fp32 transposes ----------------
// W1t[ocg][ic][u][k]  (36 contiguous floats per (ocg,ic,sg) quad -> ds_read_b128)
// W0t[(ic*9+tap)][oc]
__global__ __launch_bounds__(256) void prep_weights(const float* __restrict__ W0,
                                                    const float* __restrict__ W1,
                                                    float* __restrict__ ws) {
    int id = blockIdx.x * 256 + threadIdx.x;
    if (id < 18432) {
        int oc = id / 288, rem = id % 288, ic = rem / 9, k = rem % 9;
        int ocg = oc >> 4, u = oc & 15;
        float* w1t = (float*)((char*)ws + OFF_W1TB);
        w1t[((ocg * 32 + ic) * 16 + u) * 9 + k] = W1[((size_t)oc * 32 + ic) * 9 + k];
    } else if (id < 19008) {
        int e = id - 18432;
        int ict = e >> 5, oc = e & 31;      // ict = ic*9 + tap
        int ic = ict / 9, tap = ict % 9;
        float* w0t = (float*)((char*)ws + OFF_W0TB);
        w0t[ict * 32 + oc] = W0[(oc * 2 + ic) * 9 + tap];
    }
}

// ---------------- conv0 (2->32, 3x3, pad 1) + LIF0 -> s0 bf16 padded-NCHW ----------------
// Arithmetic bit-identical to the verified round-0 kernel.
__global__ __launch_bounds__(256) void conv0_lif(const float* __restrict__ in,
                                                 float* __restrict__ ws, int t) {
    int y = blockIdx.x, b = blockIdx.y;
    int tid = threadIdx.x;
    int x = tid & 63;
    int g = __builtin_amdgcn_readfirstlane(tid >> 6);   // oc group (8 oc)
    const float* xin = in + (size_t)((b * TSTEPS + t) * 2) * 4096;
    const float* w0t = (const float*)((const char*)ws + OFF_W0TB);
    float acc[8];
#pragma unroll
    for (int u = 0; u < 8; ++u) acc[u] = 0.f;
#pragma unroll
    for (int ic = 0; ic < 2; ++ic) {
#pragma unroll
        for (int dy = 0; dy < 3; ++dy) {
            int sy = y + dy - 1;
            bool vy = (unsigned)sy < 64u;
            const float* rp = xin + ic * 4096 + sy * 64;
#pragma unroll
            for (int dx = 0; dx < 3; ++dx) {
                int sx = x + dx - 1;
                float v = (vy && (unsigned)sx < 64u) ? rp[sx] : 0.f;
                v = fminf(fmaxf(v, 0.f), 1.f);          // clip(x,0,1)
                const float* wp = w0t + ((ic * 9 + dy * 3 + dx) * 32 + g * 8);
#pragma unroll
                for (int u = 0; u < 8; ++u) acc[u] = fmaf(v, wp[u], acc[u]);
            }
        }
    }
    // LIF0 on vm0 (NHWC fp32); spikes out to padded NCHW bf16 s0 (exact 0.0 / 1.0)
    float* vm0 = (float*)((char*)ws + OFF_VM0B);
    size_t pidx = ((size_t)(b * 4096 + y * 64 + x)) * 32 + g * 8;
    floatx4 v0 = *(floatx4*)(vm0 + pidx);
    floatx4 v1 = *(floatx4*)(vm0 + pidx + 4);
    unsigned short sp[8];
#pragma unroll
    for (int u = 0; u < 4; ++u) {
        float vm = ((v0[u] > 0.5f) ? 0.f : v0[u] * DECAY) + acc[u];
        v0[u] = vm;
        sp[u] = (vm > 0.5f) ? (unsigned short)0x3F80 : (unsigned short)0;
    }
#pragma unroll
    for (int u = 0; u < 4; ++u) {
        float vm = ((v1[u] > 0.5f) ? 0.f : v1[u] * DECAY) + acc[4 + u];
        v1[u] = vm;
        sp[4 + u] = (vm > 0.5f) ? (unsigned short)0x3F80 : (unsigned short)0;
    }
    *(floatx4*)(vm0 + pidx) = v0;
    *(floatx4*)(vm0 + pidx + 4) = v1;
    unsigned short* s0p = (unsigned short*)((char*)ws + OFF_S0PB);
#pragma unroll
    for (int u = 0; u < 8; ++u) {
        int c = g * 8 + u;
        s0p[((size_t)(b * 32 + c) * 66 + (y + 1)) * 66 + (x + 1)] = sp[u];
    }
}

// ---------------- conv1 (32->64, 3x3, pad 1) + LIF1 + fused 2x2 maxpool ----------------
// v3: weights broadcast from LDS (loaded once/block, 9 uniform ds_read_b128 per ic)
// instead of per-ic wave-uniform s_loads from global (4-5 serialized scalar round-trips
// was the stall). Block = 16 oc x 4 output rows x 64 x; 4 waves/SIMD occupancy.
// BIT-EXACT arithmetic: per accumulator, sequential fp32 fma, ic outer / k inner,
// identical chain to the verified round-3/4 kernel. s0 read direct from global (proven
// equivalent to LDS staging in round 4).
__global__ __launch_bounds__(256, 4) void conv1_lif(float* __restrict__ ws, int t) {
    __shared__ float wlds[4608];                 // [ic 32][u 16][k 9] for this block's g
    __shared__ unsigned short s1_s[4][64][18];   // [row r][x][oc_local] (pitch 18: conflict-free)
    int tid = threadIdx.x;
    int x = tid & 63;
    int sg = __builtin_amdgcn_readfirstlane(tid >> 6);   // oc quad within g (4 oc)
    int y4 = blockIdx.x, b = blockIdx.y, g = blockIdx.z; // 4 output rows, batch, 16-oc group
    int y0 = y4 * 4;

    // ---- stage this g's weight slice (4608 floats, coalesced float4) ----
    {
        const float* wsrc = (const float*)((const char*)ws + OFF_W1TB) + (size_t)g * 4608;
        for (int i = tid; i < 1152; i += 256)
            *(float4*)&wlds[i * 4] = *(const float4*)&wsrc[i * 4];
    }
    __syncthreads();

    const unsigned short* s0 = (const unsigned short*)((const char*)ws + OFF_S0PB)
                               + (size_t)b * 32 * 4356;

    float acc[4][4];   // [row r][uu]
#pragma unroll
    for (int r = 0; r < 4; ++r)
#pragma unroll
        for (int uu = 0; uu < 4; ++uu) acc[r][uu] = 0.f;

    for (int ic = 0; ic < 32; ++ic) {
        // padded rows y0..y0+5, cols x..x+2 (pad +1 and tap -1 cancel)
        const unsigned short* sc = s0 + (size_t)ic * 4356 + (size_t)y0 * 66 + x;
        float v[6][3];
#pragma unroll
        for (int rr = 0; rr < 6; ++rr)
#pragma unroll
            for (int dx = 0; dx < 3; ++dx)
                v[rr][dx] = bf2f(sc[rr * 66 + dx]);
        // 36 contiguous weights for this (ic, sg): 9 uniform ds_read_b128 (broadcast)
        const float* wq = &wlds[ic * 144 + sg * 36];
        float wv[36];
#pragma unroll
        for (int i = 0; i < 9; ++i)
            *(float4*)&wv[i * 4] = *(const float4*)&wq[i * 4];
#pragma unroll
        for (int uu = 0; uu < 4; ++uu) {
#pragma unroll
            for (int k = 0; k < 9; ++k) {
                int rr = k / 3, dx = k - rr * 3;
                float w = wv[uu * 9 + k];
                acc[0][uu] = fmaf(v[rr][dx],     w, acc[0][uu]);
                acc[1][uu] = fmaf(v[rr + 1][dx], w, acc[1][uu]);
                acc[2][uu] = fmaf(v[rr + 2][dx], w, acc[2][uu]);
                acc[3][uu] = fmaf(v[rr + 3][dx], w, acc[3][uu]);
            }
        }
    }

    // LIF1 on vm1 (NCHW fp32; s_prev = vm_prev > 0.5); spikes to LDS for pooling
    float* vm1 = (float*)((char*)ws + OFF_VM1B);
#pragma unroll
    for (int r = 0; r < 4; ++r) {
#pragma unroll
        for (int uu = 0; uu < 4; ++uu) {
            int ol = sg * 4 + uu;                 // oc_local 0..15
            int oc = g * 16 + ol;
            size_t addr = ((size_t)(b * 64 + oc) * 64 + (y0 + r)) * 64 + x;
            float vm = vm1[addr];
            vm = ((vm > 0.5f) ? 0.f : vm * DECAY) + acc[r][uu];
            vm1[addr] = vm;
            s1_s[r][x][ol] = (vm > 0.5f) ? (unsigned short)0x3F80 : (unsigned short)0;
        }
    }
    __syncthreads();

    // fused 2x2 maxpool -> flat[t*16+b] (spikes in {0,0x3F80} => max == bitwise OR)
    unsigned short* flat = (unsigned short*)((char*)ws + OFF_FLAT_BYTES)
                           + (size_t)(t * 16 + b) * 65536;
#pragma unroll
    for (int j = 0; j < 4; ++j) {
        int idx = tid + j * 256;                 // 0..1023 = ol*64 + y2l*32 + x2
        int ol = idx >> 6, y2l = (idx >> 5) & 1, x2 = idx & 31;
        int r0 = y2l * 2;
        unsigned short v = (unsigned short)(s1_s[r0][2 * x2][ol] | s1_s[r0][2 * x2 + 1][ol]
                                          | s1_s[r0 + 1][2 * x2][ol] | s1_s[r0 + 1][2 * x2 + 1][ol]);
        flat[(g * 16 + ol) * 1024 + (y4 * 2 + y2l) * 32 + x2] = v;
    }
}

// ---------------- dense0 via bf16 MFMA, hi/lo weight split (verified) ----------------
// Grid (kc, nb): linear block id = nb*64 + kc -> XCD = kc % 8, all 8 nb-blocks of one
// kc share an XCD L2 -> flat chunk HBM-fetched ~once (verified: FETCH 236->131 MB).
__global__ __launch_bounds__(256) void dense0_mfma(const float* __restrict__ D0,
                                                   float* __restrict__ ws) {
    __shared__ unsigned short A_s[256 * 72];   // [m][k] bf16
    __shared__ unsigned short Bh_s[64 * 72];   // [n][k] bf16 hi
    __shared__ unsigned short Bl_s[64 * 72];   // [n][k] bf16 lo
    int tid = threadIdx.x;
    int kc = blockIdx.x, nb = blockIdx.y;
    int lane = tid & 63, w = tid >> 6, q = lane >> 4, r = lane & 15;
    const unsigned short* flat = (const unsigned short*)((const char*)ws + OFF_FLAT_BYTES);
    const size_t kbase = (size_t)kc * KCHUNK;

    floatx4 acc[4][4];
#pragma unroll
    for (int i = 0; i < 4; ++i)
#pragma unroll
        for (int j = 0; j < 4; ++j) acc[i][j] = (floatx4){0.f, 0.f, 0.f, 0.f};

    const unsigned short* aG = flat + (size_t)tid * 65536 + kbase;
    int bn = tid & 63, bks = (tid >> 6) * 16;
    const float* bG = D0 + (size_t)(nb * 64 + bn) * 65536 + kbase + bks;

    for (int k0 = 0; k0 < KCHUNK; k0 += 64) {
        uint4 av[8];
#pragma unroll
        for (int i = 0; i < 8; ++i) av[i] = *(const uint4*)(aG + k0 + i * 8);
        float4 bv[4];
#pragma unroll
        for (int j = 0; j < 4; ++j) bv[j] = *(const float4*)(bG + k0 + j * 4);

        __syncthreads();
#pragma unroll
        for (int i = 0; i < 8; ++i) *(uint4*)&A_s[tid * 72 + i * 8] = av[i];

        float f[16];
#pragma unroll
        for (int j = 0; j < 4; ++j) { f[j*4+0]=bv[j].x; f[j*4+1]=bv[j].y; f[j*4+2]=bv[j].z; f[j*4+3]=bv[j].w; }
        unsigned hw[8], lw[8];
#pragma unroll
        for (int j = 0; j < 8; ++j) {
            unsigned short h0 = f2bf_rne(f[2*j]),   h1 = f2bf_rne(f[2*j+1]);
            unsigned short l0 = f2bf_rne(f[2*j]   - bf2f(h0));
            unsigned short l1 = f2bf_rne(f[2*j+1] - bf2f(h1));
            hw[j] = (unsigned)h0 | ((unsigned)h1 << 16);
            lw[j] = (unsigned)l0 | ((unsigned)l1 << 16);
        }
        *(uint4*)&Bh_s[bn * 72 + bks]     = make_uint4(hw[0], hw[1], hw[2], hw[3]);
        *(uint4*)&Bh_s[bn * 72 + bks + 8] = make_uint4(hw[4], hw[5], hw[6], hw[7]);
        *(uint4*)&Bl_s[bn * 72 + bks]     = make_uint4(lw[0], lw[1], lw[2], lw[3]);
        *(uint4*)&Bl_s[bn * 72 + bks + 8] = make_uint4(lw[4], lw[5], lw[6], lw[7]);
        __syncthreads();

#pragma unroll
        for (int ks = 0; ks < 64; ks += 32) {
            short8 af[4];
#pragma unroll
            for (int mi = 0; mi < 4; ++mi)
                af[mi] = *(const short8*)&A_s[(w * 64 + mi * 16 + r) * 72 + ks + q * 8];
#pragma unroll
            for (int ni = 0; ni < 4; ++ni) {
                short8 bh = *(const short8*)&Bh_s[(ni * 16 + r) * 72 + ks + q * 8];
                short8 bl = *(const short8*)&Bl_s[(ni * 16 + r) * 72 + ks + q * 8];
#pragma unroll
                for (int mi = 0; mi < 4; ++mi) {
                    acc[mi][ni] = __builtin_amdgcn_mfma_f32_16x16x32_bf16(af[mi], bh, acc[mi][ni], 0, 0, 0);
                    acc[mi][ni] = __builtin_amdgcn_mfma_f32_16x16x32_bf16(af[mi], bl, acc[mi][ni], 0, 0, 0);
                }
            }
        }
    }

    float* part = (float*)((char*)ws + OFF_PART_BYTES);
#pragma unroll
    for (int mi = 0; mi < 4; ++mi)
#pragma unroll
        for (int ni = 0; ni < 4; ++ni) {
            int m0 = w * 64 + mi * 16 + q * 4;
            int n  = nb * 64 + ni * 16 + r;
#pragma unroll
            for (int rg = 0; rg < 4; ++rg)
                part[((size_t)kc * 256 + m0 + rg) * 512 + n] = acc[mi][ni][rg];
        }
}

// ---------------- reduce split-K partials (verified) ----------------
__global__ __launch_bounds__(256) void reduce_part(float* __restrict__ ws) {
    int e = blockIdx.x * 256 + threadIdx.x;    // 0..131071
    const float* part = (const float*)((const char*)ws + OFF_PART_BYTES);
    float s = 0.f;
#pragma unroll 8
    for (int c = 0; c < KSPLIT; ++c) s += part[(size_t)c * 131072 + e];
    ((float*)((char*)ws + OFF_I_BYTES))[e] = s;
}

// ---------------- tail: LIF2 + dense1 + LIF3 + acc over all t (verified) ----------------
__global__ __launch_bounds__(512) void tail_kernel(const float* __restrict__ D1,
                                                   float* __restrict__ out,
                                                   const float* __restrict__ ws_ro) {
    __shared__ float s2l[16][512];
    __shared__ float d1l[11 * 512];
    __shared__ float pb[2][176];
    int tid = threadIdx.x;
    for (int i = tid; i < 11 * 512; i += 512) d1l[i] = D1[i];
    const float* Ibuf = (const float*)((const char*)ws_ro + OFF_I_BYTES);

    float vm2[16];
#pragma unroll
    for (int i = 0; i < 16; ++i) vm2[i] = 0.f;
    unsigned s2mask = 0;
    float vm3 = 0.f, s3 = 0.f, accv = 0.f;
    int rb = tid / 11, ro = tid % 11;
    __syncthreads();

    for (int t = 0; t < TSTEPS; ++t) {
        {
            int j = tid;
#pragma unroll
            for (int b = 0; b < 16; ++b) {
                float I = Ibuf[(size_t)(t * 16 + b) * 512 + j];
                float sp = ((s2mask >> b) & 1u) ? 1.f : 0.f;
                float vm = vm2[b] * DECAY * (1.f - sp) + I;
                vm2[b] = vm;
                unsigned sb = (vm > 0.5f) ? 1u : 0u;
                s2mask = (s2mask & ~(1u << b)) | (sb << b);
                s2l[b][j] = (float)sb;
            }
        }
        __syncthreads();
        if (tid < 352) {
            int g = tid / 176, rr = tid % 176;
            int b = rr / 11, o = rr % 11;
            float p = 0.f;
            int kbase = g * 256;
            for (int k = 0; k < 256; ++k)
                p = fmaf(s2l[b][kbase + k], d1l[o * 512 + kbase + k], p);
            pb[g][rr] = p;
        }
        __syncthreads();
        if (tid < 176) {
            float I3 = pb[0][tid] + pb[1][tid];
            float vm = vm3 * DECAY * (1.f - s3) + I3;
            vm3 = vm;
            s3 = (vm > 0.5f) ? 1.f : 0.f;
            accv += s3;
        }
        __syncthreads();
    }
    if (tid < 176) out[rb * 11 + ro] = accv * (1.f / 16.f);
}

extern "C" void kernel_launch(void* const* d_in, const int* in_sizes, int n_in,
                              void* d_out, int out_size, void* d_ws, size_t ws_size,
                              hipStream_t stream) {
    (void)in_sizes; (void)n_in; (void)out_size; (void)ws_size;
    const float* in = (const float*)d_in[0];
    const float* W0 = (const float*)d_in[1];
    const float* W1 = (const float*)d_in[2];
    const float* D0 = (const float*)d_in[3];
    const float* D1 = (const float*)d_in[4];
    float* ws = (float*)d_ws;
    float* out = (float*)d_out;

    // zero persistent LIF state (vm0, vm1) + padded s0 (guard ring) — ws is poisoned each call
    hipMemsetAsync(d_ws, 0, ZERO_BYTES, stream);
    prep_weights<<<75, 256, 0, stream>>>(W0, W1, ws);

    for (int t = 0; t < TSTEPS; ++t) {
        conv0_lif<<<dim3(64, 16), 256, 0, stream>>>(in, ws, t);
        conv1_lif<<<dim3(16, 16, 4), 256, 0, stream>>>(ws, t);
    }
    dense0_mfma<<<dim3(KSPLIT, 8), 256, 0, stream>>>(D0, ws);
    reduce_part<<<512, 256, 0, stream>>>(ws);
    tail_kernel<<<1, 512, 0, stream>>>(D1, out, ws);
}